// Round 6
// baseline (339.292 us; speedup 1.0000x reference)
//
#include <hip/hip_runtime.h>

#define D 64
#define CAP 64   // max in-degree slots per node; deg ~ Poisson(16), P(>64) ~ 1e-19

// ---------------------------------------------------------------------------
// Round-6: projection was the elephant (round-1 standalone projection ~190us;
// rounds 2-5 gather changes were all neutral because the fused kernel is
// projection-dominated: 128 scalar VMEM weight loads x 50k waves = 1.6GB
// through L1/L2). Fix:
//  - k_prep: fused pack + edge-bucket + per-TYPE node list (ballot-aggregated
//    atomics: 4 atomics/wave instead of 1/thread on 4 counters)
//  - k_gp_typed: block = 4 nodes of ONE type; W_s[t]+W_v[t] staged into 32KB
//    LDS (row-major, lane-stride-1 reads = conflict-free); gather unchanged.
// ---------------------------------------------------------------------------

__device__ __forceinline__ unsigned bf16rne(float f) {
    unsigned u = __float_as_uint(f);
    return (u + 0x7fffu + ((u >> 16) & 1u)) >> 16;   // round-to-nearest-even
}
__device__ __forceinline__ float bf_lo(unsigned w) { return __uint_as_float(w << 16); }
__device__ __forceinline__ float bf_hi(unsigned w) { return __uint_as_float(w & 0xffff0000u); }

__device__ __forceinline__ void acc8(float (&a)[8], const uint4& v) {
    a[0] += bf_lo(v.x); a[1] += bf_hi(v.x);
    a[2] += bf_lo(v.y); a[3] += bf_hi(v.y);
    a[4] += bf_lo(v.z); a[5] += bf_hi(v.z);
    a[6] += bf_lo(v.w); a[7] += bf_hi(v.w);
}

// K1: fused prep. grid covers n_nodes*32 threads (pack is the largest job).
__global__ __launch_bounds__(256) void k_prep(
    const float* __restrict__ x, const float* __restrict__ vec,
    const int* __restrict__ node_type,
    const int* __restrict__ src, const int* __restrict__ dst,
    uint4* __restrict__ packed, int* __restrict__ counts,
    int* __restrict__ slots, int* __restrict__ tcnt, int* __restrict__ tlist,
    int n_nodes, int n_edges)
{
    int idx = blockIdx.x * 256 + threadIdx.x;

    // --- pack: fp32 x|vec -> one 512B bf16 row per node ---
    if (idx < n_nodes * 32) {
        int n = idx >> 5, j = idx & 31;
        int ei = j * 8;
        const float* sp = (ei < 64) ? (x + (size_t)n * 64 + ei)
                                    : (vec + (size_t)n * 192 + (ei - 64));
        float4 f0 = *(const float4*)sp;
        float4 f1 = *(const float4*)(sp + 4);
        uint4 w;
        w.x = bf16rne(f0.x) | (bf16rne(f0.y) << 16);
        w.y = bf16rne(f0.z) | (bf16rne(f0.w) << 16);
        w.z = bf16rne(f1.x) | (bf16rne(f1.y) << 16);
        w.w = bf16rne(f1.z) | (bf16rne(f1.w) << 16);
        packed[idx] = w;
    }

    // --- edge bucket ---
    if (idx < n_edges) {
        int d = dst[idx];
        int slot = atomicAdd(&counts[d], 1);
        if (slot < CAP) slots[(size_t)d * CAP + slot] = src[idx];
    }

    // --- per-type node list, wave-aggregated atomics ---
    int lane = threadIdx.x & 63;
    int mytype = (idx < n_nodes) ? node_type[idx] : -1;
    unsigned long long ltmask = (1ull << lane) - 1ull;   // lanes below (lane<=63 ok)
#pragma unroll
    for (int t = 0; t < 4; ++t) {
        unsigned long long m = __ballot(mytype == t);
        if (m != 0ull) {                                  // wave-uniform branch
            int leader = __ffsll((long long)m) - 1;
            int base = 0;
            if (lane == leader) base = atomicAdd(&tcnt[t], __popcll(m));
            base = __shfl(base, leader);
            if (mytype == t)
                tlist[(size_t)t * n_nodes + base + __popcll(m & ltmask)] = idx;
        }
    }
}

// K2: type-batched gather + LDS-weight projection.
// grid.x = ceil(n_nodes/4) + 3  (total used groups = sum_t ceil(tcnt[t]/4))
__global__ __launch_bounds__(256) void k_gp_typed(
    const uint4* __restrict__ packed,
    const float* __restrict__ W_s, const float* __restrict__ W_v,
    const int* __restrict__ counts, const int* __restrict__ slots,
    const int* __restrict__ tcnt, const int* __restrict__ tlist,
    float* __restrict__ out_s, float* __restrict__ out_v, int n_nodes)
{
    __shared__ float WT[2][D * D];   // [0]=W_s[t], [1]=W_v[t], row-major, 32KB

    // block -> (type, group-within-type)
    int c0 = (tcnt[0] + 3) >> 2, c1 = (tcnt[1] + 3) >> 2;
    int c2 = (tcnt[2] + 3) >> 2, c3 = (tcnt[3] + 3) >> 2;
    int b = blockIdx.x, t, gi;
    if      (b < c0)                { t = 0; gi = b; }
    else if (b < c0 + c1)           { t = 1; gi = b - c0; }
    else if (b < c0 + c1 + c2)      { t = 2; gi = b - (c0 + c1); }
    else if (b < c0 + c1 + c2 + c3) { t = 3; gi = b - (c0 + c1 + c2); }
    else return;

    // stage this type's weights (coalesced float4 global -> conflict-free LDS)
    {
        const float4* Ws4 = (const float4*)(W_s + (size_t)t * D * D);
        const float4* Wv4 = (const float4*)(W_v + (size_t)t * D * D);
        float4* L0 = (float4*)&WT[0][0];
        float4* L1 = (float4*)&WT[1][0];
        for (int e = threadIdx.x; e < D * D / 4; e += 256) {
            L0[e] = Ws4[e];
            L1[e] = Wv4[e];
        }
    }
    __syncthreads();

    int wave = threadIdx.x >> 6, lane = threadIdx.x & 63;
    int ni = gi * 4 + wave;
    if (ni >= tcnt[t]) return;
    int n = tlist[(size_t)t * n_nodes + ni];

    int half = lane >> 5, hl = lane & 31;
    int cnt = counts[n]; if (cnt > CAP) cnt = CAP;
    int myidx = slots[(size_t)n * CAP + lane];   // one 256B wave load

    float a[8];
#pragma unroll
    for (int i = 0; i < 8; ++i) a[i] = 0.f;

    int k = 0;
    for (; k + 8 <= cnt; k += 8) {
        int s0 = __shfl(myidx, k     + half);
        int s1 = __shfl(myidx, k + 2 + half);
        int s2 = __shfl(myidx, k + 4 + half);
        int s3 = __shfl(myidx, k + 6 + half);
        uint4 w0 = packed[(size_t)s0 * 32 + hl];
        uint4 w1 = packed[(size_t)s1 * 32 + hl];
        uint4 w2 = packed[(size_t)s2 * 32 + hl];
        uint4 w3 = packed[(size_t)s3 * 32 + hl];
        acc8(a, w0); acc8(a, w1); acc8(a, w2); acc8(a, w3);
    }
    for (; k + 2 <= cnt; k += 2) {
        int s = __shfl(myidx, k + half);
        uint4 w = packed[(size_t)s * 32 + hl];
        acc8(a, w);
    }
    if (k < cnt) {
        int s = __shfl(myidx, k);
        if (half == 0) { uint4 w = packed[(size_t)s * 32 + hl]; acc8(a, w); }
    }
#pragma unroll
    for (int i = 0; i < 8; ++i) a[i] += __shfl_xor(a[i], 32);

    // projection: weights from LDS (lane-stride-1 = conflict-free broadcast-free)
    // agg element g=c*64+i lives at lane c*8+(i>>3), reg i&7 (verified r3/r5).
    float ys = 0.f, y0 = 0.f, y1 = 0.f, y2 = 0.f;
#pragma unroll
    for (int i = 0; i < D; ++i) {
        float as  = __shfl(a[i & 7],      (i >> 3));
        float av0 = __shfl(a[i & 7],  8 + (i >> 3));
        float av1 = __shfl(a[i & 7], 16 + (i >> 3));
        float av2 = __shfl(a[i & 7], 24 + (i >> 3));
        float wsi = WT[0][i * D + lane];
        float wvi = WT[1][i * D + lane];
        ys = fmaf(as,  wsi, ys);
        y0 = fmaf(av0, wvi, y0);
        y1 = fmaf(av1, wvi, y1);
        y2 = fmaf(av2, wvi, y2);
    }
    out_s[(size_t)n * D + lane] = ys;
    float* ov = out_v + (size_t)n * 3 * D;
    ov[lane] = y0; ov[D + lane] = y1; ov[2 * D + lane] = y2;
}

// ====================== round-5 fallback (proven) ==========================
__global__ __launch_bounds__(256) void k_pack(
    const float* __restrict__ x, const float* __restrict__ vec,
    uint4* __restrict__ packed, int* __restrict__ counts, int n_nodes)
{
    int idx = blockIdx.x * 256 + threadIdx.x;
    if (idx < n_nodes) counts[idx] = 0;
    if (idx >= n_nodes * 32) return;
    int n = idx >> 5, j = idx & 31;
    int ei = j * 8;
    const float* sp = (ei < 64) ? (x + (size_t)n * 64 + ei)
                                : (vec + (size_t)n * 192 + (ei - 64));
    float4 f0 = *(const float4*)sp;
    float4 f1 = *(const float4*)(sp + 4);
    uint4 w;
    w.x = bf16rne(f0.x) | (bf16rne(f0.y) << 16);
    w.y = bf16rne(f0.z) | (bf16rne(f0.w) << 16);
    w.z = bf16rne(f1.x) | (bf16rne(f1.y) << 16);
    w.w = bf16rne(f1.z) | (bf16rne(f1.w) << 16);
    packed[idx] = w;
}

__global__ __launch_bounds__(256) void k_bucket(
    const int* __restrict__ src, const int* __restrict__ dst,
    int* __restrict__ counts, int* __restrict__ slots, int n_edges)
{
    int e = blockIdx.x * 256 + threadIdx.x;
    if (e >= n_edges) return;
    int d = dst[e];
    int slot = atomicAdd(&counts[d], 1);
    if (slot < CAP) slots[(size_t)d * CAP + slot] = src[e];
}

__global__ __launch_bounds__(256) void k_gather_project(
    const uint4* __restrict__ packed, const int* __restrict__ node_type,
    const float* __restrict__ W_s, const float* __restrict__ W_v,
    const int* __restrict__ counts, const int* __restrict__ slots,
    float* __restrict__ out_s, float* __restrict__ out_v, int n_nodes)
{
    int wave = threadIdx.x >> 6;
    int lane = threadIdx.x & 63;
    int n = blockIdx.x * 4 + wave;
    if (n >= n_nodes) return;
    int half = lane >> 5, hl = lane & 31;
    int cnt = counts[n]; if (cnt > CAP) cnt = CAP;
    int myidx = slots[(size_t)n * CAP + lane];
    float a[8];
#pragma unroll
    for (int i = 0; i < 8; ++i) a[i] = 0.f;
    int k = 0;
    for (; k + 8 <= cnt; k += 8) {
        int s0 = __shfl(myidx, k     + half);
        int s1 = __shfl(myidx, k + 2 + half);
        int s2 = __shfl(myidx, k + 4 + half);
        int s3 = __shfl(myidx, k + 6 + half);
        uint4 w0 = packed[(size_t)s0 * 32 + hl];
        uint4 w1 = packed[(size_t)s1 * 32 + hl];
        uint4 w2 = packed[(size_t)s2 * 32 + hl];
        uint4 w3 = packed[(size_t)s3 * 32 + hl];
        acc8(a, w0); acc8(a, w1); acc8(a, w2); acc8(a, w3);
    }
    for (; k + 2 <= cnt; k += 2) {
        int s = __shfl(myidx, k + half);
        uint4 w = packed[(size_t)s * 32 + hl];
        acc8(a, w);
    }
    if (k < cnt) {
        int s = __shfl(myidx, k);
        if (half == 0) { uint4 w = packed[(size_t)s * 32 + hl]; acc8(a, w); }
    }
#pragma unroll
    for (int i = 0; i < 8; ++i) a[i] += __shfl_xor(a[i], 32);
    int t = node_type[n];
    const float* Ws = W_s + (size_t)t * D * D;
    const float* Wv = W_v + (size_t)t * D * D;
    float ys = 0.f, y0 = 0.f, y1 = 0.f, y2 = 0.f;
#pragma unroll
    for (int i = 0; i < D; ++i) {
        float as  = __shfl(a[i & 7],      (i >> 3));
        float av0 = __shfl(a[i & 7],  8 + (i >> 3));
        float av1 = __shfl(a[i & 7], 16 + (i >> 3));
        float av2 = __shfl(a[i & 7], 24 + (i >> 3));
        float wsi = Ws[i * D + lane];
        float wvi = Wv[i * D + lane];
        ys = fmaf(as,  wsi, ys);
        y0 = fmaf(av0, wvi, y0);
        y1 = fmaf(av1, wvi, y1);
        y2 = fmaf(av2, wvi, y2);
    }
    out_s[(size_t)n * D + lane] = ys;
    float* ov = out_v + (size_t)n * 3 * D;
    ov[lane] = y0; ov[D + lane] = y1; ov[2 * D + lane] = y2;
}

extern "C" void kernel_launch(void* const* d_in, const int* in_sizes, int n_in,
                              void* d_out, int out_size, void* d_ws, size_t ws_size,
                              hipStream_t stream) {
    const float* x         = (const float*)d_in[0];
    const float* vec       = (const float*)d_in[1];
    const int*   node_type = (const int*)d_in[2];
    const int*   src       = (const int*)d_in[3];
    const int*   dst       = (const int*)d_in[4];
    const float* W_s       = (const float*)d_in[5];
    const float* W_v       = (const float*)d_in[6];

    int n_nodes = in_sizes[2];
    int n_edges = in_sizes[3];

    float* out_s = (float*)d_out;
    float* out_v = out_s + (size_t)n_nodes * D;

    int eb  = (n_edges + 255) / 256;
    int nb4 = (n_nodes + 3) / 4;

    // tier-1 ws layout: [packed N*512B][slots N*CAP*4][counts N*4][tcnt 16][tlist 4N*4]
    size_t packed_bytes = (size_t)n_nodes * 32 * sizeof(uint4);   // 25.6 MB
    size_t slots_bytes  = (size_t)n_nodes * CAP * sizeof(int);    // 12.8 MB
    size_t counts_bytes = (size_t)n_nodes * sizeof(int);
    size_t tcnt_bytes   = 4 * sizeof(int);
    size_t tlist_bytes  = (size_t)n_nodes * 4 * sizeof(int);
    size_t need_t1 = packed_bytes + slots_bytes + counts_bytes + tcnt_bytes + tlist_bytes;

    if (ws_size >= need_t1) {
        uint4* packed = (uint4*)d_ws;
        int*   slots  = (int*)((char*)d_ws + packed_bytes);
        int*   counts = (int*)((char*)slots + slots_bytes);
        int*   tcnt   = (int*)((char*)counts + counts_bytes);
        int*   tlist  = (int*)((char*)tcnt + tcnt_bytes);

        // zero counts + tcnt (contiguous) in one small memset
        (void)hipMemsetAsync(counts, 0, counts_bytes + tcnt_bytes, stream);

        k_prep<<<(n_nodes * 32 + 255) / 256, 256, 0, stream>>>(
            x, vec, node_type, src, dst,
            packed, counts, slots, tcnt, tlist, n_nodes, n_edges);

        k_gp_typed<<<nb4 + 3, 256, 0, stream>>>(
            packed, W_s, W_v, counts, slots, tcnt, tlist,
            out_s, out_v, n_nodes);
        return;
    }

    // tier-2: round-5 path
    {
        uint4* packed = (uint4*)d_ws;
        int*   slots  = (int*)((char*)d_ws + packed_bytes);
        int*   counts = (int*)((char*)slots + slots_bytes);
        k_pack<<<(n_nodes * 32 + 255) / 256, 256, 0, stream>>>(
            x, vec, packed, counts, n_nodes);
        k_bucket<<<eb, 256, 0, stream>>>(src, dst, counts, slots, n_edges);
        k_gather_project<<<nb4, 256, 0, stream>>>(
            packed, node_type, W_s, W_v, counts, slots, out_s, out_v, n_nodes);
    }
}

// Round 7
// 301.135 us; speedup vs baseline: 1.1267x; 1.1267x over previous
//
#include <hip/hip_runtime.h>

#define D 64
#define CAP 64   // max in-degree slots per node; deg ~ Poisson(16), P(>64) ~ 1e-19

// ---------------------------------------------------------------------------
// Round-7: the r5/r6 counters show the hot kernel is ~95% memory-latency
// stall with loads almost fully serialized (VGPR_Count=32 -> no MLP budget;
// 140 loads x ~370cy ~= the 52k cyc/wave wall time). Fix = MLP, not layout:
//  - projection weight loads batched into register arrays (16 in flight)
//  - amdgpu_waves_per_eu(4): allow up to ~128 VGPRs
//  - gather: 16-edge unroll level (8 x 512B loads in flight per half-wave)
// Structure otherwise identical to round-5 (proven, absmax 0.125).
// ---------------------------------------------------------------------------

__device__ __forceinline__ unsigned bf16rne(float f) {
    unsigned u = __float_as_uint(f);
    return (u + 0x7fffu + ((u >> 16) & 1u)) >> 16;   // round-to-nearest-even
}
__device__ __forceinline__ float bf_lo(unsigned w) { return __uint_as_float(w << 16); }
__device__ __forceinline__ float bf_hi(unsigned w) { return __uint_as_float(w & 0xffff0000u); }

__device__ __forceinline__ void acc8(float (&a)[8], const uint4& v) {
    a[0] += bf_lo(v.x); a[1] += bf_hi(v.x);
    a[2] += bf_lo(v.y); a[3] += bf_hi(v.y);
    a[4] += bf_lo(v.z); a[5] += bf_hi(v.z);
    a[6] += bf_lo(v.w); a[7] += bf_hi(v.w);
}

__global__ __launch_bounds__(256) void k_pack(
    const float* __restrict__ x, const float* __restrict__ vec,
    uint4* __restrict__ packed, int* __restrict__ counts, int n_nodes)
{
    int idx = blockIdx.x * 256 + threadIdx.x;   // one uint4 (8 elems) per thread
    if (idx < n_nodes) counts[idx] = 0;         // zero histogram (pre-bucket)
    if (idx >= n_nodes * 32) return;
    int n = idx >> 5, j = idx & 31;
    int ei = j * 8;
    const float* sp = (ei < 64) ? (x + (size_t)n * 64 + ei)
                                : (vec + (size_t)n * 192 + (ei - 64));
    float4 f0 = *(const float4*)sp;
    float4 f1 = *(const float4*)(sp + 4);
    uint4 w;
    w.x = bf16rne(f0.x) | (bf16rne(f0.y) << 16);
    w.y = bf16rne(f0.z) | (bf16rne(f0.w) << 16);
    w.z = bf16rne(f1.x) | (bf16rne(f1.y) << 16);
    w.w = bf16rne(f1.z) | (bf16rne(f1.w) << 16);
    packed[idx] = w;
}

__global__ __launch_bounds__(256) void k_bucket(
    const int* __restrict__ src, const int* __restrict__ dst,
    int* __restrict__ counts, int* __restrict__ slots, int n_edges)
{
    int e = blockIdx.x * 256 + threadIdx.x;
    if (e >= n_edges) return;
    int d = dst[e];
    int slot = atomicAdd(&counts[d], 1);
    if (slot < CAP) slots[(size_t)d * CAP + slot] = src[e];
}

__global__ __launch_bounds__(256)
__attribute__((amdgpu_waves_per_eu(4)))   // allow ~128 VGPRs: MLP over TLP
void k_gather_project(
    const uint4* __restrict__ packed, const int* __restrict__ node_type,
    const float* __restrict__ W_s, const float* __restrict__ W_v,
    const int* __restrict__ counts, const int* __restrict__ slots,
    float* __restrict__ out_s, float* __restrict__ out_v, int n_nodes)
{
    int wave = threadIdx.x >> 6;
    int lane = threadIdx.x & 63;
    int n = blockIdx.x * 4 + wave;
    if (n >= n_nodes) return;
    int half = lane >> 5, hl = lane & 31;

    int cnt = counts[n]; if (cnt > CAP) cnt = CAP;
    int myidx = slots[(size_t)n * CAP + lane];   // one 256B wave load
    int t = node_type[n];

    float a[8];
#pragma unroll
    for (int i = 0; i < 8; ++i) a[i] = 0.f;

    int k = 0;
    // 16 edges per iteration: 8 independent 512B loads per half-wave in flight
    for (; k + 16 <= cnt; k += 16) {
        uint4 w0, w1, w2, w3, w4, w5, w6, w7;
        {
            int s0 = __shfl(myidx, k      + half);
            int s1 = __shfl(myidx, k + 2  + half);
            int s2 = __shfl(myidx, k + 4  + half);
            int s3 = __shfl(myidx, k + 6  + half);
            int s4 = __shfl(myidx, k + 8  + half);
            int s5 = __shfl(myidx, k + 10 + half);
            int s6 = __shfl(myidx, k + 12 + half);
            int s7 = __shfl(myidx, k + 14 + half);
            w0 = packed[(size_t)s0 * 32 + hl];
            w1 = packed[(size_t)s1 * 32 + hl];
            w2 = packed[(size_t)s2 * 32 + hl];
            w3 = packed[(size_t)s3 * 32 + hl];
            w4 = packed[(size_t)s4 * 32 + hl];
            w5 = packed[(size_t)s5 * 32 + hl];
            w6 = packed[(size_t)s6 * 32 + hl];
            w7 = packed[(size_t)s7 * 32 + hl];
        }
        acc8(a, w0); acc8(a, w1); acc8(a, w2); acc8(a, w3);
        acc8(a, w4); acc8(a, w5); acc8(a, w6); acc8(a, w7);
    }
    for (; k + 8 <= cnt; k += 8) {
        int s0 = __shfl(myidx, k     + half);
        int s1 = __shfl(myidx, k + 2 + half);
        int s2 = __shfl(myidx, k + 4 + half);
        int s3 = __shfl(myidx, k + 6 + half);
        uint4 w0 = packed[(size_t)s0 * 32 + hl];
        uint4 w1 = packed[(size_t)s1 * 32 + hl];
        uint4 w2 = packed[(size_t)s2 * 32 + hl];
        uint4 w3 = packed[(size_t)s3 * 32 + hl];
        acc8(a, w0); acc8(a, w1); acc8(a, w2); acc8(a, w3);
    }
    for (; k + 2 <= cnt; k += 2) {
        int s = __shfl(myidx, k + half);
        uint4 w = packed[(size_t)s * 32 + hl];
        acc8(a, w);
    }
    if (k < cnt) {                       // odd leftover: half 0 only
        int s = __shfl(myidx, k);
        if (half == 0) { uint4 w = packed[(size_t)s * 32 + hl]; acc8(a, w); }
    }
#pragma unroll
    for (int i = 0; i < 8; ++i) a[i] += __shfl_xor(a[i], 32);

    // Projection (agg elem g=c*64+i lives at lane c*8+(i>>3), reg i&7 —
    // verified r3/r5, absmax 0.125). Weight loads batched 16-at-a-time into
    // registers so they overlap; outer loop fully unrolled for pipelining.
    const float* Ws = W_s + (size_t)t * D * D + lane;
    const float* Wv = W_v + (size_t)t * D * D + lane;
    float ys = 0.f, y0 = 0.f, y1 = 0.f, y2 = 0.f;
#pragma unroll
    for (int ib = 0; ib < 8; ++ib) {
        float ws[8], wv[8];
#pragma unroll
        for (int u = 0; u < 8; ++u) {
            ws[u] = Ws[(ib * 8 + u) * D];   // coalesced 256B wave loads
            wv[u] = Wv[(ib * 8 + u) * D];
        }
#pragma unroll
        for (int u = 0; u < 8; ++u) {
            int i = ib * 8 + u;
            float as  = __shfl(a[i & 7],      (i >> 3));
            float av0 = __shfl(a[i & 7],  8 + (i >> 3));
            float av1 = __shfl(a[i & 7], 16 + (i >> 3));
            float av2 = __shfl(a[i & 7], 24 + (i >> 3));
            ys = fmaf(as,  ws[u], ys);
            y0 = fmaf(av0, wv[u], y0);
            y1 = fmaf(av1, wv[u], y1);
            y2 = fmaf(av2, wv[u], y2);
        }
    }
    out_s[(size_t)n * D + lane] = ys;
    float* ov = out_v + (size_t)n * 3 * D;
    ov[lane] = y0; ov[D + lane] = y1; ov[2 * D + lane] = y2;
}

extern "C" void kernel_launch(void* const* d_in, const int* in_sizes, int n_in,
                              void* d_out, int out_size, void* d_ws, size_t ws_size,
                              hipStream_t stream) {
    const float* x         = (const float*)d_in[0];
    const float* vec       = (const float*)d_in[1];
    const int*   node_type = (const int*)d_in[2];
    const int*   src       = (const int*)d_in[3];
    const int*   dst       = (const int*)d_in[4];
    const float* W_s       = (const float*)d_in[5];
    const float* W_v       = (const float*)d_in[6];

    int n_nodes = in_sizes[2];
    int n_edges = in_sizes[3];

    float* out_s = (float*)d_out;
    float* out_v = out_s + (size_t)n_nodes * D;

    int eb  = (n_edges + 255) / 256;
    int nb4 = (n_nodes + 3) / 4;

    // ws layout: [packed uint4 N*32][slots int N*CAP][counts int N]
    size_t packed_bytes = (size_t)n_nodes * 32 * sizeof(uint4);   // 25.6 MB
    size_t slots_bytes  = (size_t)n_nodes * CAP * sizeof(int);    // 12.8 MB

    uint4* packed = (uint4*)d_ws;
    int*   slots  = (int*)((char*)d_ws + packed_bytes);
    int*   counts = (int*)((char*)slots + slots_bytes);

    k_pack<<<(n_nodes * 32 + 255) / 256, 256, 0, stream>>>(
        x, vec, packed, counts, n_nodes);
    k_bucket<<<eb, 256, 0, stream>>>(src, dst, counts, slots, n_edges);
    k_gather_project<<<nb4, 256, 0, stream>>>(
        packed, node_type, W_s, W_v, counts, slots, out_s, out_v, n_nodes);
}